// Round 7
// baseline (388.935 us; speedup 1.0000x reference)
//
#include <hip/hip_runtime.h>

#define D_CH   1024
#define L_SEQ  8192
#define W_N    3.8349519697141029e-4f   /* 2*pi/16384 */
#define W128A  4.90873852123405e-2f     /* 2*pi/128 */

// ---------------- bf16 pack/unpack --------------------------------------
__device__ __forceinline__ float bf2f(unsigned v){
  union { float f; unsigned u; } x; x.u = v << 16;
  return x.f;
}
__device__ __forceinline__ unsigned packc(float r, float i){
  unsigned u;
  asm("v_cvt_pk_bf16_f32 %0, %1, %2" : "=v"(u) : "v"(r), "v"(i));
  return u;
}
__device__ __forceinline__ float2 upk(unsigned u){
  return make_float2(bf2f(u & 0xffffu), bf2f(u >> 16));
}
__device__ __forceinline__ float4 upk2(uint2 u){
  return make_float4(bf2f(u.x & 0xffffu), bf2f(u.x >> 16),
                     bf2f(u.y & 0xffffu), bf2f(u.y >> 16));
}
__device__ __forceinline__ float4 cmul2(float4 a, float cs, float sn){
  return make_float4(a.x*cs - a.y*sn, a.x*sn + a.y*cs,
                     a.z*cs - a.w*sn, a.z*sn + a.w*cs);
}

__device__ __host__ constexpr int bitrev3(int j){
  return ((j&1)<<2)|(j&2)|((j&4)>>2);
}

// Intra-wave LDS fence: drains this wave's DS ops WITHOUT touching vmcnt
// (global loads/stores stay in flight). sched_barrier stops hipcc from
// hoisting dependent ds_reads above the wait (rule #18).
__device__ __forceinline__ void lds_fence(){
  asm volatile("s_waitcnt lgkmcnt(0)" ::: "memory");
  __builtin_amdgcn_sched_barrier(0);
}

// ---------------- float2 (1 channel) DFT kernels (k2) -------------------
template<int SGN>
__device__ __forceinline__ void dft16(float2* x){
  const float TC[8] = {1.f, 0.9238795325f, 0.7071067812f, 0.3826834324f,
                       0.f, -0.3826834324f, -0.7071067812f, -0.9238795325f};
  const float TS[8] = {0.f, -0.3826834324f, -0.7071067812f, -0.9238795325f,
                       -1.f, -0.9238795325f, -0.7071067812f, -0.3826834324f};
#pragma unroll
  for (int len = 16; len >= 2; len >>= 1){
    const int half = len >> 1, tstep = 16 / len;
#pragma unroll
    for (int st = 0; st < 16; st += len){
#pragma unroll
      for (int j = 0; j < half; j++){
        const float wr = TC[j*tstep];
        const float wi = (SGN > 0) ? TS[j*tstep] : -TS[j*tstep];
        const int a = st + j, b = a + half;
        const float ur = x[a].x, ui = x[a].y;
        const float vr = x[b].x, vi = x[b].y;
        x[a].x = ur + vr; x[a].y = ui + vi;
        const float dr = ur - vr, di = ui - vi;
        x[b].x = dr*wr - di*wi;
        x[b].y = dr*wi + di*wr;
      }
    }
  }
}

template<int SGN>
__device__ __forceinline__ void dft8(float2* x){
  const float TC[4] = {1.f, 0.7071067812f, 0.f, -0.7071067812f};
  const float TS[4] = {0.f, -0.7071067812f, -1.f, -0.7071067812f};
#pragma unroll
  for (int len = 8; len >= 2; len >>= 1){
    const int half = len >> 1, tstep = 8 / len;
#pragma unroll
    for (int st = 0; st < 8; st += len){
#pragma unroll
      for (int j = 0; j < half; j++){
        const float wr = TC[j*tstep];
        const float wi = (SGN > 0) ? TS[j*tstep] : -TS[j*tstep];
        const int a = st + j, b = a + half;
        const float ur = x[a].x, ui = x[a].y;
        const float vr = x[b].x, vi = x[b].y;
        x[a].x = ur + vr; x[a].y = ui + vi;
        const float dr = ur - vr, di = ui - vi;
        x[b].x = dr*wr - di*wi;
        x[b].y = dr*wi + di*wr;
      }
    }
  }
}

// ---------------- float4 (2 channels) DFT kernels (k1/k3) ---------------
template<int SGN>
__device__ __forceinline__ void dft16v4(float4* x){
  const float TC[8] = {1.f, 0.9238795325f, 0.7071067812f, 0.3826834324f,
                       0.f, -0.3826834324f, -0.7071067812f, -0.9238795325f};
  const float TS[8] = {0.f, -0.3826834324f, -0.7071067812f, -0.9238795325f,
                       -1.f, -0.9238795325f, -0.7071067812f, -0.3826834324f};
#pragma unroll
  for (int len = 16; len >= 2; len >>= 1){
    const int half = len >> 1, tstep = 16 / len;
#pragma unroll
    for (int st = 0; st < 16; st += len){
#pragma unroll
      for (int j = 0; j < half; j++){
        const float wr = TC[j*tstep];
        const float wi = (SGN > 0) ? TS[j*tstep] : -TS[j*tstep];
        const int a = st + j, b = a + half;
        const float4 u = x[a], v = x[b];
        x[a] = make_float4(u.x+v.x, u.y+v.y, u.z+v.z, u.w+v.w);
        const float4 dd = make_float4(u.x-v.x, u.y-v.y, u.z-v.z, u.w-v.w);
        x[b] = make_float4(dd.x*wr - dd.y*wi, dd.x*wi + dd.y*wr,
                           dd.z*wr - dd.w*wi, dd.z*wi + dd.w*wr);
      }
    }
  }
}

// zero-top variant: x[8..15] logically zero on entry (never read).
template<int SGN>
__device__ __forceinline__ void dft16zv4(float4* x){
  const float TC[8] = {1.f, 0.9238795325f, 0.7071067812f, 0.3826834324f,
                       0.f, -0.3826834324f, -0.7071067812f, -0.9238795325f};
  const float TS[8] = {0.f, -0.3826834324f, -0.7071067812f, -0.9238795325f,
                       -1.f, -0.9238795325f, -0.7071067812f, -0.3826834324f};
#pragma unroll
  for (int j = 0; j < 8; j++){
    const float wr = TC[j];
    const float wi = (SGN > 0) ? TS[j] : -TS[j];
    const float4 u = x[j];
    x[j+8] = make_float4(u.x*wr - u.y*wi, u.x*wi + u.y*wr,
                         u.z*wr - u.w*wi, u.z*wi + u.w*wr);
  }
#pragma unroll
  for (int len = 8; len >= 2; len >>= 1){
    const int half = len >> 1, tstep = 16 / len;
#pragma unroll
    for (int st = 0; st < 16; st += len){
#pragma unroll
      for (int j = 0; j < half; j++){
        const float wr = TC[j*tstep];
        const float wi = (SGN > 0) ? TS[j*tstep] : -TS[j*tstep];
        const int a = st + j, b = a + half;
        const float4 u = x[a], v = x[b];
        x[a] = make_float4(u.x+v.x, u.y+v.y, u.z+v.z, u.w+v.w);
        const float4 dd = make_float4(u.x-v.x, u.y-v.y, u.z-v.z, u.w-v.w);
        x[b] = make_float4(dd.x*wr - dd.y*wi, dd.x*wi + dd.y*wr,
                           dd.z*wr - dd.w*wi, dd.z*wi + dd.w*wr);
      }
    }
  }
}

template<int SGN>
__device__ __forceinline__ void dft8v4(float4* x){
  const float TC[4] = {1.f, 0.7071067812f, 0.f, -0.7071067812f};
  const float TS[4] = {0.f, -0.7071067812f, -1.f, -0.7071067812f};
#pragma unroll
  for (int len = 8; len >= 2; len >>= 1){
    const int half = len >> 1, tstep = 8 / len;
#pragma unroll
    for (int st = 0; st < 8; st += len){
#pragma unroll
      for (int j = 0; j < half; j++){
        const float wr = TC[j*tstep];
        const float wi = (SGN > 0) ? TS[j*tstep] : -TS[j*tstep];
        const int a = st + j, b = a + half;
        const float4 u = x[a], v = x[b];
        x[a] = make_float4(u.x+v.x, u.y+v.y, u.z+v.z, u.w+v.w);
        const float4 dd = make_float4(u.x-v.x, u.y-v.y, u.z-v.z, u.w-v.w);
        x[b] = make_float4(dd.x*wr - dd.y*wi, dd.x*wi + dd.y*wr,
                           dd.z*wr - dd.w*wi, dd.z*wi + dd.w*wr);
      }
    }
  }
}

// ---- intra-wave fft128, 2 channels/lane (k1/k3) -------------------------
// lane = p*8 + c8 within the wave; buf = this wave's float4[64*8] (8 KiB).
// NO __syncthreads — exchange is wave-internal, ordered by lds_fence.
template<int SGN, bool ZT>
__device__ __forceinline__ void fft128w4(float4* v, float4* buf,
                                         const float2* twF, int c8, int p){
  lds_fence();                           // prior buf reads done before reuse
  if (ZT) dft16zv4<SGN>(v); else dft16v4<SGN>(v);
#pragma unroll
  for (int slot = 0; slot < 8; slot++){
    const int r = bitrev3(slot);
    const float2 t = twF[p*16 + 2*r];
    const float cs = t.x, sn = (SGN > 0) ? t.y : -t.y;
    buf[(p*8 + r)*8 + c8] = cmul2(v[slot], cs, sn);
  }
  lds_fence();                           // writes visible to whole wave
  float4 t8[8];
#pragma unroll
  for (int pp = 0; pp < 8; pp++) t8[pp] = buf[(pp*8 + p)*8 + c8]; // s=2p
  lds_fence();                           // reads complete before overwrite
  dft8v4<SGN>(t8);
#pragma unroll
  for (int t = 0; t < 8; t++) v[t] = t8[t];
#pragma unroll
  for (int slot = 8; slot < 16; slot++){
    const int r = bitrev3(slot - 8);
    const float2 t = twF[p*16 + 2*r + 1];
    const float cs = t.x, sn = (SGN > 0) ? t.y : -t.y;
    buf[(p*8 + r)*8 + c8] = cmul2(v[slot], cs, sn);
  }
  lds_fence();
#pragma unroll
  for (int pp = 0; pp < 8; pp++) t8[pp] = buf[(pp*8 + p)*8 + c8]; // s=2p+1
  dft8v4<SGN>(t8);
#pragma unroll
  for (int t = 0; t < 8; t++) v[8 + t] = t8[t];
}

// ---- intra-wave fft128, 1 channel/lane (k2); stride-9 bank padding ------
template<int SGN>
__device__ __forceinline__ void fft128w2(float2* v, float2* buf,
                                         const float2* twF, int c8, int p){
  lds_fence();
  dft16<SGN>(v);
#pragma unroll
  for (int slot = 0; slot < 8; slot++){
    const int r = bitrev3(slot);
    const float2 t = twF[p*16 + 2*r];
    const float cs = t.x, sn = (SGN > 0) ? t.y : -t.y;
    const float2 a = v[slot];
    buf[(p*8 + r)*9 + c8] = make_float2(a.x*cs - a.y*sn, a.x*sn + a.y*cs);
  }
  lds_fence();
  float2 t8[8];
#pragma unroll
  for (int pp = 0; pp < 8; pp++) t8[pp] = buf[(pp*8 + p)*9 + c8];
  lds_fence();
  dft8<SGN>(t8);
#pragma unroll
  for (int t = 0; t < 8; t++) v[t] = t8[t];
#pragma unroll
  for (int slot = 8; slot < 16; slot++){
    const int r = bitrev3(slot - 8);
    const float2 t = twF[p*16 + 2*r + 1];
    const float cs = t.x, sn = (SGN > 0) ? t.y : -t.y;
    const float2 a = v[slot];
    buf[(p*8 + r)*9 + c8] = make_float2(a.x*cs - a.y*sn, a.x*sn + a.y*cs);
  }
  lds_fence();
#pragma unroll
  for (int pp = 0; pp < 8; pp++) t8[pp] = buf[(pp*8 + p)*9 + c8];
  dft8<SGN>(t8);
#pragma unroll
  for (int t = 0; t < 8; t++) v[8 + t] = t8[t];
}

// ---------------------------------------------------------------------------
// K1: forward step1. Block = fixed (n2, d-half, mode); 8 d-tile passes of
// 64 ch (2 ch/lane); one barrier total; 2-deep register prefetch.
// ---------------------------------------------------------------------------
__global__ __launch_bounds__(256, 2)
void k1_step1(const float* __restrict__ x, const float* __restrict__ h,
              unsigned* __restrict__ Az, unsigned* __restrict__ Ah){
  __shared__ float4 xch[4][64*8];
  __shared__ float2 twF[128];
  __shared__ float2 twO[128];
  const int n2 = blockIdx.x, dh = blockIdx.y, mode = blockIdx.z;
  const int tid = threadIdx.x;
  const int wv = tid >> 6, lane = tid & 63;
  const int p = lane >> 3, c8 = lane & 7;
  const float* x1 = x + (size_t)L_SEQ * D_CH;
  unsigned* __restrict__ A = mode ? Ah : Az;
  float4* buf = xch[wv];

  float2 a0[8], a1[8], b0[8], b1[8];

  auto loadT = [&](int i, float2 (&r0)[8], float2 (&r1)[8]){
    const int d = dh*512 + i*64 + wv*16 + c8*2;
    if (mode == 0){
#pragma unroll
      for (int q = 0; q < 8; q++){
        const size_t off = (size_t)(n2 + 128*(p + 8*q)) * D_CH + d;
        r0[q] = *(const float2*)(x  + off);
        r1[q] = *(const float2*)(x1 + off);
      }
    } else {
#pragma unroll
      for (int q = 0; q < 8; q++){
        const size_t off = (size_t)(n2 + 128*(p + 8*q)) * D_CH + d;
        r0[q] = *(const float2*)(h + off);
      }
    }
  };

  auto runT = [&](int i, float2 (&r0)[8], float2 (&r1)[8]){
    const int d = dh*512 + i*64 + wv*16 + c8*2;
    float4 v[16];
    if (mode == 0){
#pragma unroll
      for (int q = 0; q < 8; q++)
        v[q] = make_float4(r0[q].x, r1[q].x, r0[q].y, r1[q].y);
    } else {
#pragma unroll
      for (int q = 0; q < 8; q++)
        v[q] = make_float4(r0[q].x, 0.f, r0[q].y, 0.f);
    }
    fft128w4<1, true>(v, buf, twF, c8, p);
#pragma unroll
    for (int c = 0; c < 2; c++)
#pragma unroll
      for (int t = 0; t < 8; t++){
        const int k1v = (2*p + c) + 16*bitrev3(t);
        if (mode == 1 && k1v > 64) continue;    // Hermitian: skip mirrors
        const float2 w = twO[k1v];
        const float4 r = cmul2(v[c*8 + t], w.x, w.y);
        *(uint2*)&A[((size_t)k1v*128 + n2)*D_CH + d] =
          make_uint2(packc(r.x, r.y), packc(r.z, r.w));
      }
  };

  loadT(0, a0, a1);                      // overlap with table build
  if (tid < 128){
    const int pp = tid >> 4, kk = tid & 15;
    float sn, cs;
    __sincosf(-W128A * (float)(pp * kk), &sn, &cs);
    twF[tid] = make_float2(cs, sn);
  } else {
    const int k1v = tid - 128;
    float sn, cs;
    __sincosf(-W_N * (float)(k1v * n2), &sn, &cs);
    twO[k1v] = make_float2(cs, sn);
  }
  __syncthreads();                       // the ONLY barrier

#pragma unroll
  for (int i = 0; i < 8; i++){
    if (i & 1){
      if (i+1 < 8) loadT(i+1, a0, a1);
      runT(i, b0, b1);
    } else {
      if (i+1 < 8) loadT(i+1, b0, b1);
      runT(i, a0, a1);
    }
  }
}

// ---------------------------------------------------------------------------
// K2 (fused): block = fixed (k1, d-quarter); 8 passes of 32 ch (1 ch/lane).
// H-spectrum in regs (Hermitian mirror reconstructed); barrier-free loop.
// ---------------------------------------------------------------------------
__global__ __launch_bounds__(256, 2)
void k2_zh(unsigned* __restrict__ Az, const unsigned* __restrict__ Ah){
  __shared__ float2 rbuf[4][128*9];
  __shared__ float2 twF[128];
  __shared__ float2 tw1[128];            // e^{-2pi i n/128}
  const int k1 = blockIdx.x, dq = blockIdx.y;
  const int tid = threadIdx.x;
  const int wv = tid >> 6, lane = tid & 63;
  const int p = lane >> 3, c8 = lane & 7;
  const int k1r = (k1 > 64) ? 128 - k1 : k1;
  float2* buf = rbuf[wv];

  unsigned haA[16], zaA[16], haB[16], zaB[16];

  auto loadT = [&](int i, unsigned (&ha)[16], unsigned (&za)[16]){
    const int d = dq*256 + i*32 + wv*8 + c8;
    const size_t bh = (size_t)k1r * 128 * D_CH + d;
    const size_t bz = (size_t)k1  * 128 * D_CH + d;
#pragma unroll
    for (int q = 0; q < 16; q++) ha[q] = Ah[bh + (size_t)(p + 8*q) * D_CH];
#pragma unroll
    for (int q = 0; q < 16; q++) za[q] = Az[bz + (size_t)(p + 8*q) * D_CH];
  };

  auto runT = [&](int i, unsigned (&ha)[16], unsigned (&za)[16]){
    const int d = dq*256 + i*32 + wv*8 + c8;
    const size_t bz = (size_t)k1 * 128 * D_CH + d;
    float2 v[16];
    if (k1 <= 64){
#pragma unroll
      for (int q = 0; q < 16; q++) v[q] = upk(ha[q]);
    } else {
      // A_h[k1,n2] = tw1[n2] * conj(A_h[128-k1,n2])
#pragma unroll
      for (int q = 0; q < 16; q++){
        const float2 a = upk(ha[q]);
        const float2 t = tw1[p + 8*q];
        v[q] = make_float2(t.x*a.x + t.y*a.y, t.y*a.x - t.x*a.y);
      }
    }
    fft128w2<1>(v, buf, twF, c8, p);
    unsigned hs[16];
    const float sc = 1.0f / 16384.0f;
#pragma unroll
    for (int j = 0; j < 16; j++) hs[j] = packc(v[j].x * sc, v[j].y * sc);

#pragma unroll
    for (int q = 0; q < 16; q++) v[q] = upk(za[q]);
    fft128w2<1>(v, buf, twF, c8, p);

#pragma unroll
    for (int j = 0; j < 16; j++){
      const float2 hv = upk(hs[j]);
      const float zr = v[j].x, zi = v[j].y;
      v[j] = make_float2(zr*hv.x - zi*hv.y, zr*hv.y + zi*hv.x);
    }

    // redistribute to natural k2 order (intra-wave, 128-slot buffer)
    lds_fence();
#pragma unroll
    for (int c = 0; c < 2; c++)
#pragma unroll
      for (int t = 0; t < 8; t++){
        const int k2i = (2*p + c) + 16*bitrev3(t);
        buf[k2i*9 + c8] = v[c*8 + t];
      }
    lds_fence();
#pragma unroll
    for (int q = 0; q < 16; q++) v[q] = buf[(p + 8*q)*9 + c8];

    fft128w2<-1>(v, buf, twF, c8, p);    // entry fence protects the reads

#pragma unroll
    for (int c = 0; c < 2; c++)
#pragma unroll
      for (int t = 0; t < 8; t++){
        const int m2 = (2*p + c) + 16*bitrev3(t);
        const float2 a = v[c*8 + t];
        Az[bz + (size_t)m2 * D_CH] = packc(a.x, a.y);
      }
  };

  loadT(0, haA, zaA);
  if (tid < 128){
    const int pp = tid >> 4, kk = tid & 15;
    float sn, cs;
    __sincosf(-W128A * (float)(pp * kk), &sn, &cs);
    twF[tid] = make_float2(cs, sn);
  } else {
    const int n = tid - 128;
    float sn, cs;
    __sincosf(-W128A * (float)n, &sn, &cs);
    tw1[n] = make_float2(cs, sn);
  }
  __syncthreads();                       // the ONLY barrier

#pragma unroll
  for (int i = 0; i < 8; i++){
    if (i & 1){
      if (i+1 < 8) loadT(i+1, haA, zaA);
      runT(i, haB, zaB);
    } else {
      if (i+1 < 8) loadT(i+1, haB, zaB);
      runT(i, haA, zaA);
    }
  }
}

// ---------------------------------------------------------------------------
// K3: inverse step2 + bias + output. Block = fixed (m2, d-quarter); 4 passes
// of 64 ch (2 ch/lane); barrier-free loop with 2-deep prefetch.
// ---------------------------------------------------------------------------
__global__ __launch_bounds__(256, 2)
void k3_inv2(const unsigned* __restrict__ Bz, const float* __restrict__ bias,
             float* __restrict__ out){
  __shared__ float4 xch[4][64*8];
  __shared__ float2 twF[128];
  __shared__ float2 twI[128];
  const int m2 = blockIdx.x, dq = blockIdx.y;
  const int tid = threadIdx.x;
  const int wv = tid >> 6, lane = tid & 63;
  const int p = lane >> 3, c8 = lane & 7;
  float4* buf = xch[wv];

  uint2 ra[16], rb[16];

  auto loadT = [&](int i, uint2 (&r)[16]){
    const int d = dq*256 + i*64 + wv*16 + c8*2;
#pragma unroll
    for (int q = 0; q < 16; q++)
      r[q] = *(const uint2*)&Bz[((size_t)(p + 8*q)*128 + m2) * D_CH + d];
  };

  auto runT = [&](int i, uint2 (&r)[16]){
    const int d = dq*256 + i*64 + wv*16 + c8*2;
    const float2 bv = *(const float2*)(bias + d);
    float4 v[16];
#pragma unroll
    for (int q = 0; q < 16; q++){
      const float2 w = twI[p + 8*q];
      v[q] = cmul2(upk2(r[q]), w.x, w.y);
    }
    fft128w4<-1, false>(v, buf, twF, c8, p);
#pragma unroll
    for (int c = 0; c < 2; c++)
#pragma unroll
      for (int t = 0; t < 8; t += 2){    // t even <=> m1 < 64
        const int m1 = (2*p + c) + 16*bitrev3(t);
        const int tseq = m2 + 128*m1;
        const float4 a = v[c*8 + t];
        *(float2*)&out[(size_t)tseq * D_CH + d] =
          make_float2(a.x + bv.x, a.z + bv.y);
        *(float2*)&out[(size_t)(L_SEQ + tseq) * D_CH + d] =
          make_float2(a.y + bv.x, a.w + bv.y);
      }
  };

  loadT(0, ra);
  if (tid < 128){
    const int pp = tid >> 4, kk = tid & 15;
    float sn, cs;
    __sincosf(-W128A * (float)(pp * kk), &sn, &cs);
    twF[tid] = make_float2(cs, sn);
  } else {
    const int k1 = tid - 128;
    float sn, cs;
    __sincosf(W_N * (float)(m2 * k1), &sn, &cs);
    twI[k1] = make_float2(cs, sn);
  }
  __syncthreads();                       // the ONLY barrier

#pragma unroll
  for (int i = 0; i < 4; i++){
    if (i & 1){
      if (i+1 < 4) loadT(i+1, ra);
      runT(i, rb);
    } else {
      if (i+1 < 4) loadT(i+1, rb);
      runT(i, ra);
    }
  }
}

// ---------------------------------------------------------------------------
extern "C" void kernel_launch(void* const* d_in, const int* in_sizes, int n_in,
                              void* d_out, int out_size, void* d_ws, size_t ws_size,
                              hipStream_t stream){
  (void)in_sizes; (void)n_in; (void)out_size;
  const float* x    = (const float*)d_in[0];
  const float* h    = (const float*)d_in[1];
  const float* bias = (const float*)d_in[2];
  float* out = (float*)d_out;

  const size_t REGION = (size_t)128 * 128 * D_CH * sizeof(unsigned); // 64 MiB
  unsigned *r1, *r2;
  if (ws_size >= 2 * REGION){
    r1 = (unsigned*)d_ws;                       // A_z -> b
    r2 = (unsigned*)((char*)d_ws + REGION);     // A_h (rows k1<=64 used)
  } else {
    r1 = (unsigned*)d_out;  // safe: k3 touches only rows ≡ m2 (mod 128) and
    r2 = (unsigned*)d_ws;   //   per-pass-disjoint d-tiles; reads precede writes
  }

  const dim3 blk(256, 1, 1);
  hipLaunchKernelGGL(k1_step1, dim3(128,2,2), blk, 0, stream, x, h, r1, r2);
  hipLaunchKernelGGL(k2_zh,    dim3(128,4,1), blk, 0, stream, r1, r2);
  hipLaunchKernelGGL(k3_inv2,  dim3(128,4,1), blk, 0, stream, r1, bias, out);
}

// Round 8
// 231.959 us; speedup vs baseline: 1.6767x; 1.6767x over previous
//
#include <hip/hip_runtime.h>

#define D_CH   1024
#define L_SEQ  8192
#define NCH    32                       /* channels per block */
#define W_N    3.8349519697141029e-4f   /* 2*pi/16384 */
#define W128A  4.90873852123405e-2f     /* 2*pi/128 */

// ---------------- bf16 pack/unpack --------------------------------------
__device__ __forceinline__ float bf2f(unsigned v){
  union { float f; unsigned u; } x; x.u = v << 16;
  return x.f;
}
// single-instruction RNE pack of (r,i) -> bf16|bf16<<16 (no builtin on gfx950)
__device__ __forceinline__ unsigned packc(float r, float i){
  unsigned u;
  asm("v_cvt_pk_bf16_f32 %0, %1, %2" : "=v"(u) : "v"(r), "v"(i));
  return u;
}
__device__ __forceinline__ float2 upk(unsigned u){
  return make_float2(bf2f(u & 0xffffu), bf2f(u >> 16));
}

__device__ __host__ constexpr int bitrev3(int j){
  return ((j&1)<<2)|(j&2)|((j&4)>>2);
}

// Soft block barrier: orders LDS traffic (lgkmcnt) + s_barrier, but does
// NOT drain vmcnt -- in-flight global loads/stores survive the barrier.
// (__syncthreads would emit s_waitcnt vmcnt(0) before s_barrier.)
// "memory" clobber + sched_barrier(0) pin LDS op order around it (rule #18).
__device__ __forceinline__ void softsync(){
  __builtin_amdgcn_sched_barrier(0);
  asm volatile("s_waitcnt lgkmcnt(0)" ::: "memory");
  __builtin_amdgcn_s_barrier();
  __builtin_amdgcn_sched_barrier(0);
}

// 16-pt DIF DFT, natural in; slot j holds X[bitrev4(j)].
template<int SGN>
__device__ __forceinline__ void dft16(float2* x){
  const float TC[8] = {1.f, 0.9238795325f, 0.7071067812f, 0.3826834324f,
                       0.f, -0.3826834324f, -0.7071067812f, -0.9238795325f};
  const float TS[8] = {0.f, -0.3826834324f, -0.7071067812f, -0.9238795325f,
                       -1.f, -0.9238795325f, -0.7071067812f, -0.3826834324f};
#pragma unroll
  for (int len = 16; len >= 2; len >>= 1){
    const int half = len >> 1, tstep = 16 / len;
#pragma unroll
    for (int st = 0; st < 16; st += len){
#pragma unroll
      for (int j = 0; j < half; j++){
        const float wr = TC[j*tstep];
        const float wi = (SGN > 0) ? TS[j*tstep] : -TS[j*tstep];
        const int a = st + j, b = a + half;
        const float ur = x[a].x, ui = x[a].y;
        const float vr = x[b].x, vi = x[b].y;
        x[a].x = ur + vr; x[a].y = ui + vi;
        const float dr = ur - vr, di = ui - vi;
        x[b].x = dr*wr - di*wi;
        x[b].y = dr*wi + di*wr;
      }
    }
  }
}

// dft16 specialized for x[8..15] == 0 (never read); stage-1 butterflies
// collapse to x[j+8] = x[j]*w(j), x[j] unchanged.
template<int SGN>
__device__ __forceinline__ void dft16z(float2* x){
  const float TC[8] = {1.f, 0.9238795325f, 0.7071067812f, 0.3826834324f,
                       0.f, -0.3826834324f, -0.7071067812f, -0.9238795325f};
  const float TS[8] = {0.f, -0.3826834324f, -0.7071067812f, -0.9238795325f,
                       -1.f, -0.9238795325f, -0.7071067812f, -0.3826834324f};
#pragma unroll
  for (int j = 0; j < 8; j++){
    const float wr = TC[j];
    const float wi = (SGN > 0) ? TS[j] : -TS[j];
    const float ur = x[j].x, ui = x[j].y;
    x[j+8].x = ur*wr - ui*wi;
    x[j+8].y = ur*wi + ui*wr;
  }
#pragma unroll
  for (int len = 8; len >= 2; len >>= 1){
    const int half = len >> 1, tstep = 16 / len;
#pragma unroll
    for (int st = 0; st < 16; st += len){
#pragma unroll
      for (int j = 0; j < half; j++){
        const float wr = TC[j*tstep];
        const float wi = (SGN > 0) ? TS[j*tstep] : -TS[j*tstep];
        const int a = st + j, b = a + half;
        const float ur = x[a].x, ui = x[a].y;
        const float vr = x[b].x, vi = x[b].y;
        x[a].x = ur + vr; x[a].y = ui + vi;
        const float dr = ur - vr, di = ui - vi;
        x[b].x = dr*wr - di*wi;
        x[b].y = dr*wi + di*wr;
      }
    }
  }
}

// 8-pt DIF DFT, natural in; slot j holds X[bitrev3(j)].
template<int SGN>
__device__ __forceinline__ void dft8(float2* x){
  const float TC[4] = {1.f, 0.7071067812f, 0.f, -0.7071067812f};
  const float TS[4] = {0.f, -0.7071067812f, -1.f, -0.7071067812f};
#pragma unroll
  for (int len = 8; len >= 2; len >>= 1){
    const int half = len >> 1, tstep = 8 / len;
#pragma unroll
    for (int st = 0; st < 8; st += len){
#pragma unroll
      for (int j = 0; j < half; j++){
        const float wr = TC[j*tstep];
        const float wi = (SGN > 0) ? TS[j*tstep] : -TS[j*tstep];
        const int a = st + j, b = a + half;
        const float ur = x[a].x, ui = x[a].y;
        const float vr = x[b].x, vi = x[b].y;
        x[a].x = ur + vr; x[a].y = ui + vi;
        const float dr = ur - vr, di = ui - vi;
        x[b].x = dr*wr - di*wi;
        x[b].y = dr*wi + di*wr;
      }
    }
  }
}

// Per-block twiddle table for fft128: twF[p*16+k] = e^{-i*2pi*p*k/128}.
__device__ __forceinline__ void build_twF(float2* twF, int tid){
  if (tid < 128){
    const int pp = tid >> 4, kk = tid & 15;
    float sn, cs;
    __sincosf(-W128A * (float)(pp * kk), &sn, &cs);
    twF[tid] = make_float2(cs, sn);
  }
}

// 128-pt DFT across 8 p-threads (p = tid>>5) x NCH channels (ch = tid&31).
// Entry: v[q] = f[p + 8q] (ZT: q<8 only, upper half logically zero).
// Exit: v[c*8+t] = F[(2p+c) + 16*bitrev3(t)].
// LDS buffer: float2[64*NCH] = 16 KiB. 3 internal SOFT barriers; caller must
// softsync() before reusing THIS lds buffer afterwards.
template<int SGN, bool ZT>
__device__ __forceinline__ void fft128(float2* v, float2* lds,
                                       const float2* twF, int ch, int p){
  if (ZT) dft16z<SGN>(v); else dft16<SGN>(v);
  // ---- phase 0: slots 0..7 (s = 2r even, r = bitrev3(slot)) ----
#pragma unroll
  for (int slot = 0; slot < 8; slot++){
    const int r = bitrev3(slot);
    const float2 t = twF[p*16 + 2*r];
    const float cs = t.x;
    const float sn = (SGN > 0) ? t.y : -t.y;
    const float2 a = v[slot];
    lds[(p*8 + r)*NCH + ch] = make_float2(a.x*cs - a.y*sn, a.x*sn + a.y*cs);
  }
  softsync();
  float2 t8[8];
#pragma unroll
  for (int pp = 0; pp < 8; pp++) t8[pp] = lds[(pp*8 + p)*NCH + ch]; // s=2p
  dft8<SGN>(t8);
#pragma unroll
  for (int t = 0; t < 8; t++) v[t] = t8[t];
  softsync();                            // reads done before phase-1 stores
  // ---- phase 1: slots 8..15 (s = 2r+1 odd) ----
#pragma unroll
  for (int slot = 8; slot < 16; slot++){
    const int r = bitrev3(slot - 8);
    const float2 t = twF[p*16 + 2*r + 1];
    const float cs = t.x;
    const float sn = (SGN > 0) ? t.y : -t.y;
    const float2 a = v[slot];
    lds[(p*8 + r)*NCH + ch] = make_float2(a.x*cs - a.y*sn, a.x*sn + a.y*cs);
  }
  softsync();
#pragma unroll
  for (int pp = 0; pp < 8; pp++) t8[pp] = lds[(pp*8 + p)*NCH + ch]; // s=2p+1
  dft8<SGN>(t8);
#pragma unroll
  for (int t = 0; t < 8; t++) v[8 + t] = t8[t];
}

// ---------------------------------------------------------------------------
// K1: forward step1 over n1 (64 nonzero of 128, zero-padded).
// A[k1,n2] = w16384^{k1 n2} * DFT128_{n1}(z[n2+128 n1]).
// mode 0: z = x[0] + i x[1]; mode 1: h (real -> only rows k1<=64 stored).
// Software-pipelined: 2 n2-tiles per block, ping-pong LDS; both tiles'
// loads issue up-front; with soft barriers tile-a stores genuinely stay
// in flight across tile-b compute (no vmcnt(0) drain at barriers).
// ---------------------------------------------------------------------------
__global__ __launch_bounds__(256, 4)
void k1_step1(const float* __restrict__ x, const float* __restrict__ h,
              unsigned* __restrict__ Az, unsigned* __restrict__ Ah){
  __shared__ float2 ldsA[64*NCH];
  __shared__ float2 ldsB[64*NCH];
  __shared__ float2 twF[128];
  __shared__ float2 twOa[128];
  __shared__ float2 twOb[128];
  const int n2a = blockIdx.x*2, n2b = n2a + 1;
  const int dg = blockIdx.y, mode = blockIdx.z;
  const int tid = threadIdx.x;
  const int ch = tid & (NCH-1), p = tid >> 5;
  const int d = dg*NCH + ch;

  // issue ALL loads for both tiles first (fetch hides under tile-a compute)
  float2 va[16], vb[16];
  if (mode == 0){
    const float* x0 = x;
    const float* x1 = x + (size_t)L_SEQ * D_CH;
#pragma unroll
    for (int q = 0; q < 8; q++){
      const size_t ra = (size_t)(n2a + 128*(p + 8*q)) * D_CH + d;
      const size_t rb = (size_t)(n2b + 128*(p + 8*q)) * D_CH + d;
      va[q] = make_float2(x0[ra], x1[ra]);
      vb[q] = make_float2(x0[rb], x1[rb]);
    }
  } else {
#pragma unroll
    for (int q = 0; q < 8; q++){
      const size_t ra = (size_t)(n2a + 128*(p + 8*q)) * D_CH + d;
      const size_t rb = (size_t)(n2b + 128*(p + 8*q)) * D_CH + d;
      va[q] = make_float2(h[ra], 0.f);
      vb[q] = make_float2(h[rb], 0.f);
    }
  }

  // per-block twiddle tables (<=3 sincos per thread)
  build_twF(twF, tid);
  if (tid >= 128){
    const int k1v = tid - 128;
    float sn, cs;
    __sincosf(-W_N * (float)(k1v * n2a), &sn, &cs);
    twOa[k1v] = make_float2(cs, sn);
    __sincosf(-W_N * (float)(k1v * n2b), &sn, &cs);
    twOb[k1v] = make_float2(cs, sn);
  }
  softsync();                            // tables visible (LDS only)

  unsigned* __restrict__ A = mode ? Ah : Az;

  // ---- tile a ----
  fft128<1, true>(va, ldsA, twF, ch, p);
#pragma unroll
  for (int c = 0; c < 2; c++){
#pragma unroll
    for (int t = 0; t < 8; t++){
      const int k1v = (2*p + c) + 16*bitrev3(t);
      if (mode == 1 && k1v > 64) continue;      // Hermitian: skip mirror rows
      const float2 w = twOa[k1v];
      const float2 a = va[c*8 + t];
      A[((size_t)k1v*128 + n2a)*D_CH + d] =
        packc(a.x*w.x - a.y*w.y, a.x*w.y + a.y*w.x);
    }
  }

  // ---- tile b (different LDS buffer -> stores_a stay in flight) ----
  fft128<1, true>(vb, ldsB, twF, ch, p);
#pragma unroll
  for (int c = 0; c < 2; c++){
#pragma unroll
    for (int t = 0; t < 8; t++){
      const int k1v = (2*p + c) + 16*bitrev3(t);
      if (mode == 1 && k1v > 64) continue;
      const float2 w = twOb[k1v];
      const float2 a = vb[c*8 + t];
      A[((size_t)k1v*128 + n2b)*D_CH + d] =
        packc(a.x*w.x - a.y*w.y, a.x*w.y + a.y*w.x);
    }
  }
}

// ---------------------------------------------------------------------------
// K2 (fused): forward step2 for h (in-register Hspec; mirror-reconstructed
// for k1>64 from Hermitian symmetry) + forward step2 for z + pointwise
// Z*H/16384 + inverse DFT over k2, in place on A_z.
// ---------------------------------------------------------------------------
__global__ __launch_bounds__(256, 4)
void k2_zh(unsigned* __restrict__ Az, const unsigned* __restrict__ Ah){
  __shared__ float2 lds[64*NCH];
  __shared__ float2 twF[128];
  __shared__ float2 tw1[128];            // e^{-2pi i n/128}
  const int k1 = blockIdx.x, dg = blockIdx.y;
  const int tid = threadIdx.x;
  const int ch = tid & (NCH-1), p = tid >> 5;
  const int d = dg*NCH + ch;
  const int k1r = (k1 > 64) ? 128 - k1 : k1;     // Hermitian mirror source
  const size_t basez = (size_t)k1  * 128 * D_CH + d;
  const size_t baseh = (size_t)k1r * 128 * D_CH + d;

  build_twF(twF, tid);
  if (tid < 128){
    float sn, cs;
    __sincosf(-W128A * (float)tid, &sn, &cs);
    tw1[tid] = make_float2(cs, sn);
  }

  // issue all independent loads up front (MLP)
  unsigned ha[16], za[16];
#pragma unroll
  for (int q = 0; q < 16; q++)
    ha[q] = Ah[baseh + (size_t)(p + 8*q) * D_CH];
#pragma unroll
  for (int q = 0; q < 16; q++)
    za[q] = Az[basez + (size_t)(p + 8*q) * D_CH];

  softsync();                            // tables visible (LDS only)

  // ---- H: forward 128-pt over n2, keep spectrum packed in regs ----
  float2 v[16];
  if (k1 <= 64){
#pragma unroll
    for (int q = 0; q < 16; q++) v[q] = upk(ha[q]);
  } else {
    // A_h[k1,n2] = tw1[n2] * conj(A_h[128-k1,n2])
#pragma unroll
    for (int q = 0; q < 16; q++){
      const float2 a = upk(ha[q]);
      const float2 t = tw1[p + 8*q];
      v[q] = make_float2(t.x*a.x + t.y*a.y, t.y*a.x - t.x*a.y);
    }
  }
  fft128<1, false>(v, lds, twF, ch, p);
  unsigned hs[16];
  const float sc = 1.0f / 16384.0f;      // fold ifft scale into Hspec
#pragma unroll
  for (int i = 0; i < 16; i++) hs[i] = packc(v[i].x * sc, v[i].y * sc);
  softsync();                            // lds reads done before z-fft stores

  // ---- Z: forward 128-pt over n2 ----
#pragma unroll
  for (int q = 0; q < 16; q++) v[q] = upk(za[q]);
  fft128<1, false>(v, lds, twF, ch, p);

  // ---- pointwise multiply (orders match) ----
#pragma unroll
  for (int i = 0; i < 16; i++){
    const float2 hv = upk(hs[i]);
    const float zr = v[i].x, zi = v[i].y;
    v[i] = make_float2(zr*hv.x - zi*hv.y, zr*hv.y + zi*hv.x);
  }

  // ---- redistribute to natural k2 order: v[q] = Y[p+8q] ----
  softsync();                            // protect fft128's lds reads
  float2 w[8];
  // phase A: k2 < 64  (t even)
#pragma unroll
  for (int c = 0; c < 2; c++)
#pragma unroll
    for (int t = 0; t < 8; t += 2){
      const int k2 = (2*p + c) + 16*bitrev3(t);
      lds[k2*NCH + ch] = v[c*8 + t];
    }
  softsync();
#pragma unroll
  for (int q = 0; q < 8; q++) w[q] = lds[(p + 8*q)*NCH + ch];
  softsync();
  // phase B: k2 >= 64 (t odd)
#pragma unroll
  for (int c = 0; c < 2; c++)
#pragma unroll
    for (int t = 1; t < 8; t += 2){
      const int k2 = (2*p + c) + 16*bitrev3(t) - 64;
      lds[k2*NCH + ch] = v[c*8 + t];
    }
  softsync();
#pragma unroll
  for (int q = 0; q < 8; q++) v[8 + q] = lds[(p + 8*q)*NCH + ch];
  softsync();                            // reads done before inverse stores
#pragma unroll
  for (int q = 0; q < 8; q++) v[q] = w[q];

  // ---- inverse 128-pt over k2 ----
  fft128<-1, false>(v, lds, twF, ch, p); // v[c*8+t] = b at m2=(2p+c)+16*bitrev3(t)

#pragma unroll
  for (int c = 0; c < 2; c++){
#pragma unroll
    for (int t = 0; t < 8; t++){
      const int m2 = (2*p + c) + 16*bitrev3(t);
      const float2 a = v[c*8 + t];
      Az[basez + (size_t)m2 * D_CH] = packc(a.x, a.y);
    }
  }
}

// ---------------------------------------------------------------------------
// K3: inverse step2 over k1 + bias + output write. Software-pipelined:
// 2 m2-tiles per block, ping-pong LDS; tile-a stores overlap tile-b fft.
// y[0,t,d] = Re(w)+bias, y[1,t,d] = Im(w)+bias, t = m2 + 128*m1, m1 < 64.
// ---------------------------------------------------------------------------
__global__ __launch_bounds__(256, 4)
void k3_inv2(const unsigned* __restrict__ Bz, const float* __restrict__ bias,
             float* __restrict__ out){
  __shared__ float2 ldsA[64*NCH];
  __shared__ float2 ldsB[64*NCH];
  __shared__ float2 twF[128];
  __shared__ float2 twIa[128];
  __shared__ float2 twIb[128];
  const int m2a = blockIdx.x*2, m2b = m2a + 1;
  const int dg = blockIdx.y;
  const int tid = threadIdx.x;
  const int ch = tid & (NCH-1), p = tid >> 5;
  const int d = dg*NCH + ch;
  const float bv = bias[d];

  // issue ALL loads for both tiles first
  unsigned rawa[16], rawb[16];
#pragma unroll
  for (int q = 0; q < 16; q++){
    const int k1 = p + 8*q;
    rawa[q] = Bz[((size_t)k1*128 + m2a) * D_CH + d];
    rawb[q] = Bz[((size_t)k1*128 + m2b) * D_CH + d];
  }

  build_twF(twF, tid);
  if (tid >= 128){
    const int k1 = tid - 128;
    float sn, cs;
    __sincosf(W_N * (float)(m2a * k1), &sn, &cs);    // e^{+2pi i m2 k1 /16384}
    twIa[k1] = make_float2(cs, sn);
    __sincosf(W_N * (float)(m2b * k1), &sn, &cs);
    twIb[k1] = make_float2(cs, sn);
  }
  softsync();                            // tables visible (LDS only)

  float2 v[16];
  // ---- tile a ----
#pragma unroll
  for (int q = 0; q < 16; q++){
    const float2 w = twIa[p + 8*q];
    const float2 a = upk(rawa[q]);
    v[q] = make_float2(a.x*w.x - a.y*w.y, a.x*w.y + a.y*w.x);
  }
  fft128<-1, false>(v, ldsA, twF, ch, p);
#pragma unroll
  for (int c = 0; c < 2; c++){
#pragma unroll
    for (int t = 0; t < 8; t += 2){      // t even <=> bitrev3(t)<4 <=> m1 < 64
      const int m1 = (2*p + c) + 16*bitrev3(t);
      const int tseq = m2a + 128*m1;
      const float2 a = v[c*8 + t];
      out[(size_t)tseq * D_CH + d]            = a.x + bv;
      out[(size_t)(L_SEQ + tseq) * D_CH + d]  = a.y + bv;
    }
  }

  // ---- tile b (different LDS buffer; stores_a stay in flight) ----
#pragma unroll
  for (int q = 0; q < 16; q++){
    const float2 w = twIb[p + 8*q];
    const float2 a = upk(rawb[q]);
    v[q] = make_float2(a.x*w.x - a.y*w.y, a.x*w.y + a.y*w.x);
  }
  fft128<-1, false>(v, ldsB, twF, ch, p);
#pragma unroll
  for (int c = 0; c < 2; c++){
#pragma unroll
    for (int t = 0; t < 8; t += 2){
      const int m1 = (2*p + c) + 16*bitrev3(t);
      const int tseq = m2b + 128*m1;
      const float2 a = v[c*8 + t];
      out[(size_t)tseq * D_CH + d]            = a.x + bv;
      out[(size_t)(L_SEQ + tseq) * D_CH + d]  = a.y + bv;
    }
  }
}

// ---------------------------------------------------------------------------
extern "C" void kernel_launch(void* const* d_in, const int* in_sizes, int n_in,
                              void* d_out, int out_size, void* d_ws, size_t ws_size,
                              hipStream_t stream){
  (void)in_sizes; (void)n_in; (void)out_size;
  const float* x    = (const float*)d_in[0];
  const float* h    = (const float*)d_in[1];
  const float* bias = (const float*)d_in[2];
  float* out = (float*)d_out;

  const size_t REGION = (size_t)128 * 128 * D_CH * sizeof(unsigned); // 64 MiB
  unsigned *r1, *r2;
  if (ws_size >= 2 * REGION){
    r1 = (unsigned*)d_ws;                       // A_z -> b
    r2 = (unsigned*)((char*)d_ws + REGION);     // A_h (rows k1<=64 used)
  } else {
    r1 = (unsigned*)d_out;  // safe: K3 per-tile reads are row-disjoint from
    r2 = (unsigned*)d_ws;   //   its other tile's writes (m2a != m2b mod 128)
  }

  const dim3 blk(256, 1, 1);
  hipLaunchKernelGGL(k1_step1, dim3(64,32,2), blk, 0, stream, x, h, r1, r2);
  hipLaunchKernelGGL(k2_zh,    dim3(128,32,1), blk, 0, stream, r1, r2);
  hipLaunchKernelGGL(k3_inv2,  dim3(64,32,1), blk, 0, stream, r1, bias, out);
}

// Round 9
// 214.122 us; speedup vs baseline: 1.8164x; 1.0833x over previous
//
#include <hip/hip_runtime.h>

#define D_CH   1024
#define L_SEQ  8192
#define NCH    32                       /* channels per block */
#define W_N    3.8349519697141029e-4f   /* 2*pi/16384 */
#define W128A  4.90873852123405e-2f     /* 2*pi/128 */

// ---------------- bf16 pack/unpack --------------------------------------
__device__ __forceinline__ float bf2f(unsigned v){
  union { float f; unsigned u; } x; x.u = v << 16;
  return x.f;
}
// single-instruction RNE pack of (r,i) -> bf16|bf16<<16 (no builtin on gfx950)
__device__ __forceinline__ unsigned packc(float r, float i){
  unsigned u;
  asm("v_cvt_pk_bf16_f32 %0, %1, %2" : "=v"(u) : "v"(r), "v"(i));
  return u;
}
__device__ __forceinline__ float2 upk(unsigned u){
  return make_float2(bf2f(u & 0xffffu), bf2f(u >> 16));
}

__device__ __host__ constexpr int bitrev3(int j){
  return ((j&1)<<2)|(j&2)|((j&4)>>2);
}

// Soft block barrier: orders LDS traffic (lgkmcnt) + s_barrier, but does
// NOT drain vmcnt -- in-flight global loads/stores survive the barrier.
__device__ __forceinline__ void softsync(){
  __builtin_amdgcn_sched_barrier(0);
  asm volatile("s_waitcnt lgkmcnt(0)" ::: "memory");
  __builtin_amdgcn_s_barrier();
  __builtin_amdgcn_sched_barrier(0);
}

// 16-pt DIF DFT, natural in; slot j holds X[bitrev4(j)].
template<int SGN>
__device__ __forceinline__ void dft16(float2* x){
  const float TC[8] = {1.f, 0.9238795325f, 0.7071067812f, 0.3826834324f,
                       0.f, -0.3826834324f, -0.7071067812f, -0.9238795325f};
  const float TS[8] = {0.f, -0.3826834324f, -0.7071067812f, -0.9238795325f,
                       -1.f, -0.9238795325f, -0.7071067812f, -0.3826834324f};
#pragma unroll
  for (int len = 16; len >= 2; len >>= 1){
    const int half = len >> 1, tstep = 16 / len;
#pragma unroll
    for (int st = 0; st < 16; st += len){
#pragma unroll
      for (int j = 0; j < half; j++){
        const float wr = TC[j*tstep];
        const float wi = (SGN > 0) ? TS[j*tstep] : -TS[j*tstep];
        const int a = st + j, b = a + half;
        const float ur = x[a].x, ui = x[a].y;
        const float vr = x[b].x, vi = x[b].y;
        x[a].x = ur + vr; x[a].y = ui + vi;
        const float dr = ur - vr, di = ui - vi;
        x[b].x = dr*wr - di*wi;
        x[b].y = dr*wi + di*wr;
      }
    }
  }
}

// dft16 specialized for x[8..15] == 0 (never read); stage-1 butterflies
// collapse to x[j+8] = x[j]*w(j), x[j] unchanged.
template<int SGN>
__device__ __forceinline__ void dft16z(float2* x){
  const float TC[8] = {1.f, 0.9238795325f, 0.7071067812f, 0.3826834324f,
                       0.f, -0.3826834324f, -0.7071067812f, -0.9238795325f};
  const float TS[8] = {0.f, -0.3826834324f, -0.7071067812f, -0.9238795325f,
                       -1.f, -0.9238795325f, -0.7071067812f, -0.3826834324f};
#pragma unroll
  for (int j = 0; j < 8; j++){
    const float wr = TC[j];
    const float wi = (SGN > 0) ? TS[j] : -TS[j];
    const float ur = x[j].x, ui = x[j].y;
    x[j+8].x = ur*wr - ui*wi;
    x[j+8].y = ur*wi + ui*wr;
  }
#pragma unroll
  for (int len = 8; len >= 2; len >>= 1){
    const int half = len >> 1, tstep = 16 / len;
#pragma unroll
    for (int st = 0; st < 16; st += len){
#pragma unroll
      for (int j = 0; j < half; j++){
        const float wr = TC[j*tstep];
        const float wi = (SGN > 0) ? TS[j*tstep] : -TS[j*tstep];
        const int a = st + j, b = a + half;
        const float ur = x[a].x, ui = x[a].y;
        const float vr = x[b].x, vi = x[b].y;
        x[a].x = ur + vr; x[a].y = ui + vi;
        const float dr = ur - vr, di = ui - vi;
        x[b].x = dr*wr - di*wi;
        x[b].y = dr*wi + di*wr;
      }
    }
  }
}

// 8-pt DIF DFT, natural in; slot j holds X[bitrev3(j)].
template<int SGN>
__device__ __forceinline__ void dft8(float2* x){
  const float TC[4] = {1.f, 0.7071067812f, 0.f, -0.7071067812f};
  const float TS[4] = {0.f, -0.7071067812f, -1.f, -0.7071067812f};
#pragma unroll
  for (int len = 8; len >= 2; len >>= 1){
    const int half = len >> 1, tstep = 8 / len;
#pragma unroll
    for (int st = 0; st < 8; st += len){
#pragma unroll
      for (int j = 0; j < half; j++){
        const float wr = TC[j*tstep];
        const float wi = (SGN > 0) ? TS[j*tstep] : -TS[j*tstep];
        const int a = st + j, b = a + half;
        const float ur = x[a].x, ui = x[a].y;
        const float vr = x[b].x, vi = x[b].y;
        x[a].x = ur + vr; x[a].y = ui + vi;
        const float dr = ur - vr, di = ui - vi;
        x[b].x = dr*wr - di*wi;
        x[b].y = dr*wi + di*wr;
      }
    }
  }
}

// Per-block twiddle table for fft128: twF[p*16+k] = e^{-i*2pi*p*k/128}.
__device__ __forceinline__ void build_twF(float2* twF, int tid){
  if (tid < 128){
    const int pp = tid >> 4, kk = tid & 15;
    float sn, cs;
    __sincosf(-W128A * (float)(pp * kk), &sn, &cs);
    twF[tid] = make_float2(cs, sn);
  }
}

// 128-pt DFT across 8 p-threads (p = tid>>5) x NCH channels (ch = tid&31).
template<int SGN, bool ZT>
__device__ __forceinline__ void fft128(float2* v, float2* lds,
                                       const float2* twF, int ch, int p){
  if (ZT) dft16z<SGN>(v); else dft16<SGN>(v);
  // ---- phase 0: slots 0..7 (s = 2r even, r = bitrev3(slot)) ----
#pragma unroll
  for (int slot = 0; slot < 8; slot++){
    const int r = bitrev3(slot);
    const float2 t = twF[p*16 + 2*r];
    const float cs = t.x;
    const float sn = (SGN > 0) ? t.y : -t.y;
    const float2 a = v[slot];
    lds[(p*8 + r)*NCH + ch] = make_float2(a.x*cs - a.y*sn, a.x*sn + a.y*cs);
  }
  softsync();
  float2 t8[8];
#pragma unroll
  for (int pp = 0; pp < 8; pp++) t8[pp] = lds[(pp*8 + p)*NCH + ch]; // s=2p
  dft8<SGN>(t8);
#pragma unroll
  for (int t = 0; t < 8; t++) v[t] = t8[t];
  softsync();                            // reads done before phase-1 stores
  // ---- phase 1: slots 8..15 (s = 2r+1 odd) ----
#pragma unroll
  for (int slot = 8; slot < 16; slot++){
    const int r = bitrev3(slot - 8);
    const float2 t = twF[p*16 + 2*r + 1];
    const float cs = t.x;
    const float sn = (SGN > 0) ? t.y : -t.y;
    const float2 a = v[slot];
    lds[(p*8 + r)*NCH + ch] = make_float2(a.x*cs - a.y*sn, a.x*sn + a.y*cs);
  }
  softsync();
#pragma unroll
  for (int pp = 0; pp < 8; pp++) t8[pp] = lds[(pp*8 + p)*NCH + ch]; // s=2p+1
  dft8<SGN>(t8);
#pragma unroll
  for (int t = 0; t < 8; t++) v[8 + t] = t8[t];
}

// ---------------------------------------------------------------------------
// K1: forward step1 over n1 (64 nonzero of 128, zero-padded).
// x/h loads are NON-TEMPORAL (single-use stream) so they don't evict the
// A intermediates from L3 between k1 and k2.
// ---------------------------------------------------------------------------
__global__ __launch_bounds__(256, 4)
void k1_step1(const float* __restrict__ x, const float* __restrict__ h,
              unsigned* __restrict__ Az, unsigned* __restrict__ Ah){
  __shared__ float2 ldsA[64*NCH];
  __shared__ float2 ldsB[64*NCH];
  __shared__ float2 twF[128];
  __shared__ float2 twOa[128];
  __shared__ float2 twOb[128];
  const int n2a = blockIdx.x*2, n2b = n2a + 1;
  const int dg = blockIdx.y, mode = blockIdx.z;
  const int tid = threadIdx.x;
  const int ch = tid & (NCH-1), p = tid >> 5;
  const int d = dg*NCH + ch;

  // issue ALL loads for both tiles first (fetch hides under tile-a compute)
  float2 va[16], vb[16];
  if (mode == 0){
    const float* x0 = x;
    const float* x1 = x + (size_t)L_SEQ * D_CH;
#pragma unroll
    for (int q = 0; q < 8; q++){
      const size_t ra = (size_t)(n2a + 128*(p + 8*q)) * D_CH + d;
      const size_t rb = (size_t)(n2b + 128*(p + 8*q)) * D_CH + d;
      va[q] = make_float2(__builtin_nontemporal_load(x0 + ra),
                          __builtin_nontemporal_load(x1 + ra));
      vb[q] = make_float2(__builtin_nontemporal_load(x0 + rb),
                          __builtin_nontemporal_load(x1 + rb));
    }
  } else {
#pragma unroll
    for (int q = 0; q < 8; q++){
      const size_t ra = (size_t)(n2a + 128*(p + 8*q)) * D_CH + d;
      const size_t rb = (size_t)(n2b + 128*(p + 8*q)) * D_CH + d;
      va[q] = make_float2(__builtin_nontemporal_load(h + ra), 0.f);
      vb[q] = make_float2(__builtin_nontemporal_load(h + rb), 0.f);
    }
  }

  // per-block twiddle tables (<=3 sincos per thread)
  build_twF(twF, tid);
  if (tid >= 128){
    const int k1v = tid - 128;
    float sn, cs;
    __sincosf(-W_N * (float)(k1v * n2a), &sn, &cs);
    twOa[k1v] = make_float2(cs, sn);
    __sincosf(-W_N * (float)(k1v * n2b), &sn, &cs);
    twOb[k1v] = make_float2(cs, sn);
  }
  softsync();                            // tables visible (LDS only)

  unsigned* __restrict__ A = mode ? Ah : Az;

  // ---- tile a ----
  fft128<1, true>(va, ldsA, twF, ch, p);
#pragma unroll
  for (int c = 0; c < 2; c++){
#pragma unroll
    for (int t = 0; t < 8; t++){
      const int k1v = (2*p + c) + 16*bitrev3(t);
      if (mode == 1 && k1v > 64) continue;      // Hermitian: skip mirror rows
      const float2 w = twOa[k1v];
      const float2 a = va[c*8 + t];
      A[((size_t)k1v*128 + n2a)*D_CH + d] =
        packc(a.x*w.x - a.y*w.y, a.x*w.y + a.y*w.x);
    }
  }

  // ---- tile b (different LDS buffer -> stores_a stay in flight) ----
  fft128<1, true>(vb, ldsB, twF, ch, p);
#pragma unroll
  for (int c = 0; c < 2; c++){
#pragma unroll
    for (int t = 0; t < 8; t++){
      const int k1v = (2*p + c) + 16*bitrev3(t);
      if (mode == 1 && k1v > 64) continue;
      const float2 w = twOb[k1v];
      const float2 a = vb[c*8 + t];
      A[((size_t)k1v*128 + n2b)*D_CH + d] =
        packc(a.x*w.x - a.y*w.y, a.x*w.y + a.y*w.x);
    }
  }
}

// ---------------------------------------------------------------------------
// K2 (fused): forward step2 for h (in-register Hspec; mirror-reconstructed
// for k1>64) + forward step2 for z + pointwise Z*H/16384 + inverse DFT over
// k2, in place on A_z. Loads stay NORMAL (A_h mirror rows are read twice;
// A_z lines are rewritten in place).
// ---------------------------------------------------------------------------
__global__ __launch_bounds__(256, 4)
void k2_zh(unsigned* __restrict__ Az, const unsigned* __restrict__ Ah){
  __shared__ float2 lds[64*NCH];
  __shared__ float2 twF[128];
  __shared__ float2 tw1[128];            // e^{-2pi i n/128}
  const int k1 = blockIdx.x, dg = blockIdx.y;
  const int tid = threadIdx.x;
  const int ch = tid & (NCH-1), p = tid >> 5;
  const int d = dg*NCH + ch;
  const int k1r = (k1 > 64) ? 128 - k1 : k1;     // Hermitian mirror source
  const size_t basez = (size_t)k1  * 128 * D_CH + d;
  const size_t baseh = (size_t)k1r * 128 * D_CH + d;

  build_twF(twF, tid);
  if (tid < 128){
    float sn, cs;
    __sincosf(-W128A * (float)tid, &sn, &cs);
    tw1[tid] = make_float2(cs, sn);
  }

  // issue all independent loads up front (MLP)
  unsigned ha[16], za[16];
#pragma unroll
  for (int q = 0; q < 16; q++)
    ha[q] = Ah[baseh + (size_t)(p + 8*q) * D_CH];
#pragma unroll
  for (int q = 0; q < 16; q++)
    za[q] = Az[basez + (size_t)(p + 8*q) * D_CH];

  softsync();                            // tables visible (LDS only)

  // ---- H: forward 128-pt over n2, keep spectrum packed in regs ----
  float2 v[16];
  if (k1 <= 64){
#pragma unroll
    for (int q = 0; q < 16; q++) v[q] = upk(ha[q]);
  } else {
    // A_h[k1,n2] = tw1[n2] * conj(A_h[128-k1,n2])
#pragma unroll
    for (int q = 0; q < 16; q++){
      const float2 a = upk(ha[q]);
      const float2 t = tw1[p + 8*q];
      v[q] = make_float2(t.x*a.x + t.y*a.y, t.y*a.x - t.x*a.y);
    }
  }
  fft128<1, false>(v, lds, twF, ch, p);
  unsigned hs[16];
  const float sc = 1.0f / 16384.0f;      // fold ifft scale into Hspec
#pragma unroll
  for (int i = 0; i < 16; i++) hs[i] = packc(v[i].x * sc, v[i].y * sc);
  softsync();                            // lds reads done before z-fft stores

  // ---- Z: forward 128-pt over n2 ----
#pragma unroll
  for (int q = 0; q < 16; q++) v[q] = upk(za[q]);
  fft128<1, false>(v, lds, twF, ch, p);

  // ---- pointwise multiply (orders match) ----
#pragma unroll
  for (int i = 0; i < 16; i++){
    const float2 hv = upk(hs[i]);
    const float zr = v[i].x, zi = v[i].y;
    v[i] = make_float2(zr*hv.x - zi*hv.y, zr*hv.y + zi*hv.x);
  }

  // ---- redistribute to natural k2 order: v[q] = Y[p+8q] ----
  softsync();                            // protect fft128's lds reads
  float2 w[8];
  // phase A: k2 < 64  (t even)
#pragma unroll
  for (int c = 0; c < 2; c++)
#pragma unroll
    for (int t = 0; t < 8; t += 2){
      const int k2 = (2*p + c) + 16*bitrev3(t);
      lds[k2*NCH + ch] = v[c*8 + t];
    }
  softsync();
#pragma unroll
  for (int q = 0; q < 8; q++) w[q] = lds[(p + 8*q)*NCH + ch];
  softsync();
  // phase B: k2 >= 64 (t odd)
#pragma unroll
  for (int c = 0; c < 2; c++)
#pragma unroll
    for (int t = 1; t < 8; t += 2){
      const int k2 = (2*p + c) + 16*bitrev3(t) - 64;
      lds[k2*NCH + ch] = v[c*8 + t];
    }
  softsync();
#pragma unroll
  for (int q = 0; q < 8; q++) v[8 + q] = lds[(p + 8*q)*NCH + ch];
  softsync();                            // reads done before inverse stores
#pragma unroll
  for (int q = 0; q < 8; q++) v[q] = w[q];

  // ---- inverse 128-pt over k2 ----
  fft128<-1, false>(v, lds, twF, ch, p); // v[c*8+t] = b at m2=(2p+c)+16*bitrev3(t)

#pragma unroll
  for (int c = 0; c < 2; c++){
#pragma unroll
    for (int t = 0; t < 8; t++){
      const int m2 = (2*p + c) + 16*bitrev3(t);
      const float2 a = v[c*8 + t];
      Az[basez + (size_t)m2 * D_CH] = packc(a.x, a.y);
    }
  }
}

// ---------------------------------------------------------------------------
// K3: inverse step2 over k1 + bias + output write. Bz reads and out writes
// are NON-TEMPORAL (both single-use) so they don't churn L3.
// ---------------------------------------------------------------------------
__global__ __launch_bounds__(256, 4)
void k3_inv2(const unsigned* __restrict__ Bz, const float* __restrict__ bias,
             float* __restrict__ out){
  __shared__ float2 ldsA[64*NCH];
  __shared__ float2 ldsB[64*NCH];
  __shared__ float2 twF[128];
  __shared__ float2 twIa[128];
  __shared__ float2 twIb[128];
  const int m2a = blockIdx.x*2, m2b = m2a + 1;
  const int dg = blockIdx.y;
  const int tid = threadIdx.x;
  const int ch = tid & (NCH-1), p = tid >> 5;
  const int d = dg*NCH + ch;
  const float bv = bias[d];

  // issue ALL loads for both tiles first
  unsigned rawa[16], rawb[16];
#pragma unroll
  for (int q = 0; q < 16; q++){
    const int k1 = p + 8*q;
    rawa[q] = __builtin_nontemporal_load(&Bz[((size_t)k1*128 + m2a) * D_CH + d]);
    rawb[q] = __builtin_nontemporal_load(&Bz[((size_t)k1*128 + m2b) * D_CH + d]);
  }

  build_twF(twF, tid);
  if (tid >= 128){
    const int k1 = tid - 128;
    float sn, cs;
    __sincosf(W_N * (float)(m2a * k1), &sn, &cs);    // e^{+2pi i m2 k1 /16384}
    twIa[k1] = make_float2(cs, sn);
    __sincosf(W_N * (float)(m2b * k1), &sn, &cs);
    twIb[k1] = make_float2(cs, sn);
  }
  softsync();                            // tables visible (LDS only)

  float2 v[16];
  // ---- tile a ----
#pragma unroll
  for (int q = 0; q < 16; q++){
    const float2 w = twIa[p + 8*q];
    const float2 a = upk(rawa[q]);
    v[q] = make_float2(a.x*w.x - a.y*w.y, a.x*w.y + a.y*w.x);
  }
  fft128<-1, false>(v, ldsA, twF, ch, p);
#pragma unroll
  for (int c = 0; c < 2; c++){
#pragma unroll
    for (int t = 0; t < 8; t += 2){      // t even <=> bitrev3(t)<4 <=> m1 < 64
      const int m1 = (2*p + c) + 16*bitrev3(t);
      const int tseq = m2a + 128*m1;
      const float2 a = v[c*8 + t];
      __builtin_nontemporal_store(a.x + bv, &out[(size_t)tseq * D_CH + d]);
      __builtin_nontemporal_store(a.y + bv, &out[(size_t)(L_SEQ + tseq) * D_CH + d]);
    }
  }

  // ---- tile b (different LDS buffer; stores_a stay in flight) ----
#pragma unroll
  for (int q = 0; q < 16; q++){
    const float2 w = twIb[p + 8*q];
    const float2 a = upk(rawb[q]);
    v[q] = make_float2(a.x*w.x - a.y*w.y, a.x*w.y + a.y*w.x);
  }
  fft128<-1, false>(v, ldsB, twF, ch, p);
#pragma unroll
  for (int c = 0; c < 2; c++){
#pragma unroll
    for (int t = 0; t < 8; t += 2){
      const int m1 = (2*p + c) + 16*bitrev3(t);
      const int tseq = m2b + 128*m1;
      const float2 a = v[c*8 + t];
      __builtin_nontemporal_store(a.x + bv, &out[(size_t)tseq * D_CH + d]);
      __builtin_nontemporal_store(a.y + bv, &out[(size_t)(L_SEQ + tseq) * D_CH + d]);
    }
  }
}

// ---------------------------------------------------------------------------
extern "C" void kernel_launch(void* const* d_in, const int* in_sizes, int n_in,
                              void* d_out, int out_size, void* d_ws, size_t ws_size,
                              hipStream_t stream){
  (void)in_sizes; (void)n_in; (void)out_size;
  const float* x    = (const float*)d_in[0];
  const float* h    = (const float*)d_in[1];
  const float* bias = (const float*)d_in[2];
  float* out = (float*)d_out;

  const size_t REGION = (size_t)128 * 128 * D_CH * sizeof(unsigned); // 64 MiB
  unsigned *r1, *r2;
  if (ws_size >= 2 * REGION){
    r1 = (unsigned*)d_ws;                       // A_z -> b
    r2 = (unsigned*)((char*)d_ws + REGION);     // A_h (rows k1<=64 used)
  } else {
    r1 = (unsigned*)d_out;  // safe: K3 per-tile reads are row-disjoint from
    r2 = (unsigned*)d_ws;   //   its other tile's writes (m2a != m2b mod 128)
  }

  const dim3 blk(256, 1, 1);
  hipLaunchKernelGGL(k1_step1, dim3(64,32,2), blk, 0, stream, x, h, r1, r2);
  hipLaunchKernelGGL(k2_zh,    dim3(128,32,1), blk, 0, stream, r1, r2);
  hipLaunchKernelGGL(k3_inv2,  dim3(64,32,1), blk, 0, stream, r1, bias, out);
}